// Round 7
// baseline (291.158 us; speedup 1.0000x reference)
//
#include <hip/hip_runtime.h>
#include <cstdint>

#define BLK 256
#define ABLK 512           // agg kernels: 8 waves/block -> 32 waves/CU at 4 blk/CU
#define EJ 4
#define CHUNK (BLK * EJ)   // 1024 edges per bucket block (R6 lesson: EJ=16 ->
                           // grid 391 = 1.5 blk/CU = 14% occupancy in bucket)
#define SLB 6              // slice = 64 nodes
#define SLN 64
#define SCAP 1536          // mean 1024 @ E=1.6M/NS=1563; +16 sigma; 128-aligned
#define NSMAX 1600         // n <= 102400 supported

// Fixed-point scales for integer atomics (R2/R3 lesson: FP atomicAdd on LDS
// lowers to a CAS retry loop on gfx950 -> 9x stall; int ds_add_u32 is native).
#define S1   2097152.0f        // 2^21, layer-1/2 feature accumulators
#define IS1  (1.0f / 2097152.0f)
#define DSC  16777216.0f       // 2^24, degree accumulator
#define IDSC (1.0f / 16777216.0f)

__device__ inline unsigned short f2bf(float f) {  // RNE
  unsigned u = __float_as_uint(f);
  return (unsigned short)((u + 0x7FFF + ((u >> 16) & 1)) >> 16);
}
__device__ inline float bflo(unsigned u) { return __uint_as_float(u << 16); }
__device__ inline float bfhi(unsigned u) { return __uint_as_float(u & 0xFFFF0000u); }

// ---------------- init per-slice cursors to slice base ----------------
__global__ __launch_bounds__(BLK) void k_zeroC(int* __restrict__ cur, int NS) {
  int s = blockIdx.x * BLK + threadIdx.x;
  if (s < NS) cur[s] = s * SCAP;
}

// ---------------- bucket edges into fixed-capacity slice bins ----------------
// R3-verified structure: LDS histogram -> one batched reservation per
// (block,slice) -> LDS-cursor scatter. R4 (degI fusion) and R5 (per-edge
// global atomic) both regressed. R7: CHUNK 4096->1024 for occupancy.
// bpk[p] = { (dstLocal<<20) | src, ew }   (requires n <= 2^20, dstLocal < 64)
__global__ __launch_bounds__(BLK) void k_bucket(const int* __restrict__ src,
                                                const int* __restrict__ dst,
                                                const float* __restrict__ ew,
                                                int* __restrict__ cur,
                                                int2* __restrict__ bpk,
                                                int n, int E, int NS) {
  __shared__ int c[NSMAX], b[NSMAX], o[NSMAX];
  int tid = threadIdx.x;
  for (int i = tid; i < NS; i += BLK) { c[i] = 0; o[i] = 0; }
  __syncthreads();
  int base = blockIdx.x * CHUNK;
  int dloc[EJ];
#pragma unroll
  for (int j = 0; j < EJ; j++) {
    int idx = base + j * BLK + tid;
    int d = -1;
    if (idx < E) {
      d = dst[idx];
      if ((unsigned)d >= (unsigned)n) d = -1;
    }
    dloc[j] = d;
    if (d >= 0) atomicAdd(&c[d >> SLB], 1);
  }
  __syncthreads();
  for (int s = tid; s < NS; s += BLK)
    if (c[s]) b[s] = atomicAdd(&cur[s], c[s]);
  __syncthreads();
#pragma unroll
  for (int j = 0; j < EJ; j++) {
    int idx = base + j * BLK + tid;
    int d = dloc[j];
    if (d >= 0) {
      int s = d >> SLB;
      int p = b[s] + atomicAdd(&o[s], 1);
      p = min(max(p, s * SCAP), (s + 1) * SCAP - 1);  // clamp into slice
      int packed = ((d & (SLN - 1)) << 20) | (src[idx] & 0xFFFFF);
      bpk[p] = make_int2(packed, __float_as_int(ew[idx]));
    }
  }
}

// ---------------- per-slice weighted in-degree -> dinv; pad slices ----------
// Pads each slice's edge list to a multiple of 128 with {0,0} dummies
// (dl=0, w=0 -> contributes nothing) so agg loops run maskless/clampless.
__global__ __launch_bounds__(BLK) void k_dinv(int2* __restrict__ bpk,
                                              int* __restrict__ cur,
                                              float* __restrict__ dinv, int n) {
  __shared__ int wsum[SLN];
  int s = blockIdx.x, tid = threadIdx.x;
  int node0 = s << SLB;
  int e0 = s * SCAP;
  int cnt = min(cur[s], e0 + SCAP) - e0;
  int cntP = min((cnt + 127) & ~127, SCAP);  // SCAP is 128-aligned
  if (tid < SLN) wsum[tid] = 0;
  for (int e = cnt + tid; e < cntP; e += BLK) bpk[e0 + e] = make_int2(0, 0);
  if (tid == 0) cur[s] = e0 + cntP;
  __syncthreads();
  for (int e = e0 + tid; e < e0 + cnt; e += BLK) {
    int2 pk = bpk[e];
    atomicAdd(&wsum[(unsigned)pk.x >> 20],
              __float2int_rn(__int_as_float(pk.y) * DSC));
  }
  __syncthreads();
  if (tid < SLN && node0 + tid < n)
    dinv[node0 + tid] = rsqrtf(1.0f + wsum[tid] * IDSC);  // deg >= 1 (self loop)
}

// ---------------- GEMM1: h1s[n,64](bf16x2) = dinv * (x[n,128] @ W1[128,64]) --
__global__ __launch_bounds__(BLK) void k_gemm1(const float* __restrict__ x,
                                               const float* __restrict__ W,
                                               const float* __restrict__ dinv,
                                               unsigned* __restrict__ h1s, int n) {
  __shared__ float Ws[128 * 64];
  __shared__ float xs[16][128];
  int tid = threadIdx.x;
  const float4* W4 = (const float4*)W;
  float4* Ws4 = (float4*)Ws;
#pragma unroll
  for (int i = 0; i < 8; i++) Ws4[tid + i * BLK] = W4[tid + i * BLK];
  int row0 = blockIdx.x * 16;
  int nrows = min(16, n - row0);
  const float4* x4 = (const float4*)(x + (size_t)row0 * 128);
  float4* xs4 = (float4*)xs;
  for (int i = tid; i < nrows * 32; i += BLK) xs4[i] = x4[i];
  __syncthreads();
  int col = tid & 63, rg = tid >> 6;  // wave-uniform rg -> xs reads broadcast
  float acc0 = 0.f, acc1 = 0.f, acc2 = 0.f, acc3 = 0.f;
#pragma unroll 4
  for (int k = 0; k < 128; k++) {
    float w = Ws[k * 64 + col];
    acc0 += xs[rg][k] * w;
    acc1 += xs[rg + 4][k] * w;
    acc2 += xs[rg + 8][k] * w;
    acc3 += xs[rg + 12][k] * w;
  }
  int r = row0 + rg;
  int rc0 = min(r, n - 1), rc1 = min(r + 4, n - 1),
      rc2 = min(r + 8, n - 1), rc3 = min(r + 12, n - 1);
  float v0 = acc0 * dinv[rc0], v1 = acc1 * dinv[rc1],
        v2 = acc2 * dinv[rc2], v3 = acc3 * dinv[rc3];
  float p0 = __shfl_xor(v0, 1, 64), p1 = __shfl_xor(v1, 1, 64),
        p2 = __shfl_xor(v2, 1, 64), p3 = __shfl_xor(v3, 1, 64);
  if ((col & 1) == 0) {
    int dw = col >> 1;
    unsigned u0 = (unsigned)f2bf(v0) | ((unsigned)f2bf(p0) << 16);
    unsigned u1 = (unsigned)f2bf(v1) | ((unsigned)f2bf(p1) << 16);
    unsigned u2 = (unsigned)f2bf(v2) | ((unsigned)f2bf(p2) << 16);
    unsigned u3 = (unsigned)f2bf(v3) | ((unsigned)f2bf(p3) << 16);
    if (r < n)      h1s[(size_t)r * 32 + dw]        = u0;
    if (r + 4 < n)  h1s[(size_t)(r + 4) * 32 + dw]  = u1;
    if (r + 8 < n)  h1s[(size_t)(r + 8) * 32 + dw]  = u2;
    if (r + 12 < n) h1s[(size_t)(r + 12) * 32 + dw] = u3;
  }
}

// ---------------- layer-1: slice-LDS aggregate + bias + ReLU + GEMM2 --------
// Block = slice of 64 nodes, 512 threads. R7: 16 lanes/edge, lane owns a
// dword-pair (uint2 gather) -> 4 edges per wave-pass (2x bookkeeping
// amortization vs half-wave/edge); maskless (slices 128-padded by k_dinv).
// Fixed-point int LDS accumulators (native ds_add_u32), two planes, stride 33.
#define U1 4
__global__ __launch_bounds__(ABLK) void k_agg1s(const float* __restrict__ dinv,
                                                const int2* __restrict__ bpk,
                                                const int* __restrict__ cur,
                                                const unsigned* __restrict__ h1s,
                                                const float* __restrict__ b1,
                                                const float* __restrict__ W2,
                                                unsigned* __restrict__ h2s, int n) {
  __shared__ int accE[SLN * 33];
  __shared__ int accO[SLN * 33];
  __shared__ float W2s[64 * 16];
  __shared__ float dv[SLN];
  __shared__ float bb[64];
  int tid = threadIdx.x;
  int s = blockIdx.x;
  int node0 = s << SLB;
  int sn = min(SLN, n - node0);
  for (int i = tid; i < SLN * 33; i += ABLK) { accE[i] = 0; accO[i] = 0; }
  for (int i = tid; i < 1024; i += ABLK) W2s[i] = W2[i];
  if (tid < SLN) dv[tid] = (tid < sn) ? dinv[node0 + tid] : 0.f;
  if (tid < 64) bb[tid] = b1[tid];
  int e0 = s * SCAP;
  int cnt = min(cur[s], e0 + SCAP) - e0;  // multiple of 128 (padded)
  __syncthreads();

  int w = tid >> 6;         // wave 0..7
  int g4 = (tid >> 4) & 3;  // edge sub-slot within wave
  int l = tid & 15;         // owns dwords 2l, 2l+1 (features 4l..4l+3)
  for (int base = w * 16; base < cnt; base += 128) {
    int2 pk[U1];
#pragma unroll
    for (int u = 0; u < U1; u++) pk[u] = bpk[e0 + base + g4 + 4 * u];
    uint2 gg[U1];
#pragma unroll
    for (int u = 0; u < U1; u++)
      gg[u] = *(const uint2*)(h1s +
               (size_t)(unsigned)(pk[u].x & 0xFFFFF) * 32 + 2 * l);
#pragma unroll
    for (int u = 0; u < U1; u++) {
      int a = (int)((unsigned)pk[u].x >> 20) * 33 + 2 * l;
      float wt = __int_as_float(pk[u].y) * S1;
      atomicAdd(&accE[a],     __float2int_rn(wt * bflo(gg[u].x)));
      atomicAdd(&accO[a],     __float2int_rn(wt * bfhi(gg[u].x)));
      atomicAdd(&accE[a + 1], __float2int_rn(wt * bflo(gg[u].y)));
      atomicAdd(&accO[a + 1], __float2int_rn(wt * bfhi(gg[u].y)));
    }
  }
  __syncthreads();
  // F1: in-place relu rows: plane[k&1][node*33+(k>>1)] = relu(dv*(acc+self)+b1[k])
  for (int i = tid; i < SLN * 64; i += ABLK) {
    int node = i >> 6, k = i & 63;
    if (node < sn) {
      int v = node0 + node;
      unsigned us = h1s[(size_t)v * 32 + (k >> 1)];  // self (pre-scaled by dinv)
      float self = (k & 1) ? bfhi(us) : bflo(us);
      int* pl = (k & 1) ? accO : accE;
      int idx = node * 33 + (k >> 1);
      float a = pl[idx] * IS1;
      pl[idx] = __float_as_int(fmaxf(dv[node] * (a + self) + bb[k], 0.f));
    }
  }
  __syncthreads();
  // F2: GEMM2, 16 threads per node, 32 nodes per batch; h2s = dinv * (relu @ W2)
  int j = tid & 15;
  for (int nb = 0; nb < SLN; nb += 32) {
    int node = nb + (tid >> 4);  // 0..31
    float p = 0.f;
#pragma unroll
    for (int k = 0; k < 64; k++) {
      float rv = __int_as_float(((k & 1) ? accO : accE)[node * 33 + (k >> 1)]);
      p += rv * W2s[k * 16 + j];
    }
    p *= dv[node];
    float pp = __shfl_xor(p, 1, 64);
    if (node < sn && (j & 1) == 0)
      h2s[(size_t)(node0 + node) * 8 + (j >> 1)] =
          (unsigned)f2bf(p) | ((unsigned)f2bf(pp) << 16);
  }
}

// ---------------- layer-2: slice-LDS aggregate + bias + log_softmax ---------
// 512 threads. R7: 4 lanes/edge, lane owns dword-pair -> 16 edges/wave-pass,
// maskless. acc stride 17.
__global__ __launch_bounds__(ABLK) void k_agg2s(const float* __restrict__ dinv,
                                                const int2* __restrict__ bpk,
                                                const int* __restrict__ cur,
                                                const unsigned* __restrict__ h2s,
                                                const float* __restrict__ b2,
                                                float* __restrict__ out, int n) {
  __shared__ int acc2[SLN * 17];
  int tid = threadIdx.x;
  int s = blockIdx.x;
  int node0 = s << SLB;
  int sn = min(SLN, n - node0);
  for (int i = tid; i < SLN * 17; i += ABLK) acc2[i] = 0;
  int e0 = s * SCAP;
  int cnt = min(cur[s], e0 + SCAP) - e0;  // multiple of 128 (padded)
  __syncthreads();

  int w = tid >> 6;          // wave 0..7
  int eg = (tid >> 2) & 15;  // edge slot within wave
  int m = tid & 3;           // owns dwords 2m, 2m+1 (features 4m..4m+3)
  for (int base = w * 16; base < cnt; base += 128) {
    int2 pk = bpk[e0 + base + eg];
    uint2 gg = *(const uint2*)(h2s +
               (size_t)(unsigned)(pk.x & 0xFFFFF) * 8 + 2 * m);
    int a = (int)((unsigned)pk.x >> 20) * 17 + 4 * m;
    float wt = __int_as_float(pk.y) * S1;
    atomicAdd(&acc2[a],     __float2int_rn(wt * bflo(gg.x)));
    atomicAdd(&acc2[a + 1], __float2int_rn(wt * bfhi(gg.x)));
    atomicAdd(&acc2[a + 2], __float2int_rn(wt * bflo(gg.y)));
    atomicAdd(&acc2[a + 3], __float2int_rn(wt * bfhi(gg.y)));
  }
  __syncthreads();
  // finalize: 16 threads per node, 32 nodes/batch, log_softmax in 16-lane group
  int f = tid & 15;
  for (int nb = 0; nb < SLN; nb += 32) {
    int node = nb + (tid >> 4);  // 0..31
    bool ok = node < sn;
    int v = node0 + min(node, sn - 1);
    float val = 0.f;
    if (ok) {
      float di = dinv[v];
      unsigned us = h2s[(size_t)v * 8 + (f >> 1)];  // self (pre-scaled)
      float self = (f & 1) ? bfhi(us) : bflo(us);
      val = di * (acc2[node * 17 + f] * IS1 + self) + b2[f];
    }
    float m2 = val;
    m2 = fmaxf(m2, __shfl_xor(m2, 1, 64));
    m2 = fmaxf(m2, __shfl_xor(m2, 2, 64));
    m2 = fmaxf(m2, __shfl_xor(m2, 4, 64));
    m2 = fmaxf(m2, __shfl_xor(m2, 8, 64));
    float ex = expf(val - m2);
    float ssum = ex;
    ssum += __shfl_xor(ssum, 1, 64);
    ssum += __shfl_xor(ssum, 2, 64);
    ssum += __shfl_xor(ssum, 4, 64);
    ssum += __shfl_xor(ssum, 8, 64);
    if (ok) out[(size_t)v * 16 + f] = val - m2 - logf(ssum);
  }
}

extern "C" void kernel_launch(void* const* d_in, const int* in_sizes, int n_in,
                              void* d_out, int out_size, void* d_ws, size_t ws_size,
                              hipStream_t stream) {
  const float* x  = (const float*)d_in[0];
  const int*   ei = (const int*)d_in[1];   // int32 [2,E]
  const float* ew = (const float*)d_in[2];
  const float* W1 = (const float*)d_in[3];
  const float* b1 = (const float*)d_in[4];
  const float* W2 = (const float*)d_in[5];
  const float* b2 = (const float*)d_in[6];
  float* out = (float*)d_out;

  int n = in_sizes[0] / 128;
  int E = in_sizes[2];
  const int* src = ei;
  const int* dst = ei + E;

  int NS = ((n - 1) >> SLB) + 1;  // 1563 for n=100k
  size_t padE = (size_t)NS * SCAP;

  char* wp = (char*)d_ws;
  auto alloc = [&](size_t bytes) -> char* {
    char* r = wp;
    wp += (bytes + 15) & ~(size_t)15;
    return r;
  };
  int*      cur  = (int*)alloc((size_t)(NS + 4) * 4);
  int2*     bpk  = (int2*)alloc(padE * 8);
  float*    dinv = (float*)alloc((size_t)n * 4);
  unsigned* h1s  = (unsigned*)alloc((size_t)n * 32 * 4);
  unsigned* h2s  = (unsigned*)alloc((size_t)n * 8 * 4);

  int gC = (E + CHUNK - 1) / CHUNK;  // 1563

  k_zeroC<<<(NS + BLK - 1) / BLK, BLK, 0, stream>>>(cur, NS);
  k_bucket<<<gC, BLK, 0, stream>>>(src, dst, ew, cur, bpk, n, E, NS);
  k_dinv<<<NS, BLK, 0, stream>>>(bpk, cur, dinv, n);
  k_gemm1<<<(n + 15) / 16, BLK, 0, stream>>>(x, W1, dinv, h1s, n);
  k_agg1s<<<NS, ABLK, 0, stream>>>(dinv, bpk, cur, h1s, b1, W2, h2s, n);
  k_agg2s<<<NS, ABLK, 0, stream>>>(dinv, bpk, cur, h2s, b2, out, n);
}

// Round 8
// 244.555 us; speedup vs baseline: 1.1906x; 1.1906x over previous
//
#include <hip/hip_runtime.h>
#include <cstdint>

#define BLK 256
#define ABLK 512           // agg kernels: 8 waves/block
#define BBLK 1024          // bucket: 16 waves/block (R7 lesson: occupancy must
                           // come from BLK, not grid — batching needs CHUNK>>NS)
#define EJ 4
#define CHUNK (BBLK * EJ)  // 4096 edges per bucket block, grid 391
#define SLB 6              // slice = 64 nodes
#define SLN 64
#define SCAP 1536          // mean 1024 @ E=1.6M/NS=1563; +16 sigma; 128-aligned
#define NSMAX 1600         // n <= 102400 supported

// Fixed-point scales for integer atomics (R2/R3 lesson: FP atomicAdd on LDS
// lowers to a CAS retry loop on gfx950 -> 9x stall; int ds_add_u32 is native).
#define S1   2097152.0f        // 2^21, layer-1/2 feature accumulators
#define IS1  (1.0f / 2097152.0f)
#define DSC  16777216.0f       // 2^24, degree accumulator
#define IDSC (1.0f / 16777216.0f)

__device__ inline unsigned short f2bf(float f) {  // RNE
  unsigned u = __float_as_uint(f);
  return (unsigned short)((u + 0x7FFF + ((u >> 16) & 1)) >> 16);
}
__device__ inline float bflo(unsigned u) { return __uint_as_float(u << 16); }
__device__ inline float bfhi(unsigned u) { return __uint_as_float(u & 0xFFFF0000u); }

// ---------------- init per-slice cursors to slice base ----------------
__global__ __launch_bounds__(BLK) void k_zeroC(int* __restrict__ cur, int NS) {
  int s = blockIdx.x * BLK + threadIdx.x;
  if (s < NS) cur[s] = s * SCAP;
}

// ---------------- bucket edges into fixed-capacity slice bins ----------------
// LDS histogram -> one batched reservation per (block,slice) -> LDS-cursor
// scatter. Single LDS array: c[s] is count, then global base, then cursor.
// 16 waves/block so the scattered 8B stores have TLP to hide under
// (R5: per-edge global atomics 153us; R7: CHUNK=1024 degenerate batching 83us).
// bpk[p] = { (dstLocal<<20) | src, ew }   (requires n <= 2^20, dstLocal < 64)
__global__ __launch_bounds__(BBLK) void k_bucket(const int* __restrict__ src,
                                                 const int* __restrict__ dst,
                                                 const float* __restrict__ ew,
                                                 int* __restrict__ cur,
                                                 int2* __restrict__ bpk,
                                                 int n, int E, int NS) {
  __shared__ int c[NSMAX];
  int tid = threadIdx.x;
  for (int i = tid; i < NS; i += BBLK) c[i] = 0;
  __syncthreads();
  int base = blockIdx.x * CHUNK;
  int dloc[EJ];
#pragma unroll
  for (int j = 0; j < EJ; j++) {
    int idx = base + j * BBLK + tid;
    int d = -1;
    if (idx < E) {
      d = dst[idx];
      if ((unsigned)d >= (unsigned)n) d = -1;
    }
    dloc[j] = d;
    if (d >= 0) atomicAdd(&c[d >> SLB], 1);
  }
  __syncthreads();
  for (int s = tid; s < NS; s += BBLK) {
    int cc = c[s];
    if (cc) c[s] = atomicAdd(&cur[s], cc);  // c[s] becomes this block's cursor
  }
  __syncthreads();
#pragma unroll
  for (int j = 0; j < EJ; j++) {
    int idx = base + j * BBLK + tid;
    int d = dloc[j];
    if (d >= 0) {
      int s = d >> SLB;
      int p = atomicAdd(&c[s], 1);
      p = min(max(p, s * SCAP), (s + 1) * SCAP - 1);  // clamp into slice
      int packed = ((d & (SLN - 1)) << 20) | (src[idx] & 0xFFFFF);
      bpk[p] = make_int2(packed, __float_as_int(ew[idx]));
    }
  }
}

// ---------------- per-slice weighted in-degree -> dinv; pad slices ----------
// Pads each slice's edge list to a multiple of 128 with {0,0} dummies
// (dl=0, w=0 -> contributes nothing) so agg loops run maskless/clampless.
__global__ __launch_bounds__(BLK) void k_dinv(int2* __restrict__ bpk,
                                              int* __restrict__ cur,
                                              float* __restrict__ dinv, int n) {
  __shared__ int wsum[SLN];
  int s = blockIdx.x, tid = threadIdx.x;
  int node0 = s << SLB;
  int e0 = s * SCAP;
  int cnt = min(cur[s], e0 + SCAP) - e0;
  int cntP = min((cnt + 127) & ~127, SCAP);  // SCAP is 128-aligned
  if (tid < SLN) wsum[tid] = 0;
  for (int e = cnt + tid; e < cntP; e += BLK) bpk[e0 + e] = make_int2(0, 0);
  if (tid == 0) cur[s] = e0 + cntP;
  __syncthreads();
  for (int e = e0 + tid; e < e0 + cnt; e += BLK) {
    int2 pk = bpk[e];
    atomicAdd(&wsum[(unsigned)pk.x >> 20],
              __float2int_rn(__int_as_float(pk.y) * DSC));
  }
  __syncthreads();
  if (tid < SLN && node0 + tid < n)
    dinv[node0 + tid] = rsqrtf(1.0f + wsum[tid] * IDSC);  // deg >= 1 (self loop)
}

// ---------------- GEMM1: h1s[n,64](bf16x2) = dinv * (x[n,128] @ W1[128,64]) --
__global__ __launch_bounds__(BLK) void k_gemm1(const float* __restrict__ x,
                                               const float* __restrict__ W,
                                               const float* __restrict__ dinv,
                                               unsigned* __restrict__ h1s, int n) {
  __shared__ float Ws[128 * 64];
  __shared__ float xs[16][128];
  int tid = threadIdx.x;
  const float4* W4 = (const float4*)W;
  float4* Ws4 = (float4*)Ws;
#pragma unroll
  for (int i = 0; i < 8; i++) Ws4[tid + i * BLK] = W4[tid + i * BLK];
  int row0 = blockIdx.x * 16;
  int nrows = min(16, n - row0);
  const float4* x4 = (const float4*)(x + (size_t)row0 * 128);
  float4* xs4 = (float4*)xs;
  for (int i = tid; i < nrows * 32; i += BLK) xs4[i] = x4[i];
  __syncthreads();
  int col = tid & 63, rg = tid >> 6;  // wave-uniform rg -> xs reads broadcast
  float acc0 = 0.f, acc1 = 0.f, acc2 = 0.f, acc3 = 0.f;
#pragma unroll 4
  for (int k = 0; k < 128; k++) {
    float w = Ws[k * 64 + col];
    acc0 += xs[rg][k] * w;
    acc1 += xs[rg + 4][k] * w;
    acc2 += xs[rg + 8][k] * w;
    acc3 += xs[rg + 12][k] * w;
  }
  int r = row0 + rg;
  int rc0 = min(r, n - 1), rc1 = min(r + 4, n - 1),
      rc2 = min(r + 8, n - 1), rc3 = min(r + 12, n - 1);
  float v0 = acc0 * dinv[rc0], v1 = acc1 * dinv[rc1],
        v2 = acc2 * dinv[rc2], v3 = acc3 * dinv[rc3];
  float p0 = __shfl_xor(v0, 1, 64), p1 = __shfl_xor(v1, 1, 64),
        p2 = __shfl_xor(v2, 1, 64), p3 = __shfl_xor(v3, 1, 64);
  if ((col & 1) == 0) {
    int dw = col >> 1;
    unsigned u0 = (unsigned)f2bf(v0) | ((unsigned)f2bf(p0) << 16);
    unsigned u1 = (unsigned)f2bf(v1) | ((unsigned)f2bf(p1) << 16);
    unsigned u2 = (unsigned)f2bf(v2) | ((unsigned)f2bf(p2) << 16);
    unsigned u3 = (unsigned)f2bf(v3) | ((unsigned)f2bf(p3) << 16);
    if (r < n)      h1s[(size_t)r * 32 + dw]        = u0;
    if (r + 4 < n)  h1s[(size_t)(r + 4) * 32 + dw]  = u1;
    if (r + 8 < n)  h1s[(size_t)(r + 8) * 32 + dw]  = u2;
    if (r + 12 < n) h1s[(size_t)(r + 12) * 32 + dw] = u3;
  }
}

// ---------------- layer-1: slice-LDS aggregate + bias + ReLU + GEMM2 --------
// Block = slice of 64 nodes, 512 threads. 16 lanes/edge, lane owns a
// dword-pair (uint2 gather) -> 4 edges per wave-pass; maskless (slices
// 128-padded by k_dinv). Fixed-point int LDS accumulators (native ds_add_u32),
// two planes, stride 33.
#define U1 4
__global__ __launch_bounds__(ABLK) void k_agg1s(const float* __restrict__ dinv,
                                                const int2* __restrict__ bpk,
                                                const int* __restrict__ cur,
                                                const unsigned* __restrict__ h1s,
                                                const float* __restrict__ b1,
                                                const float* __restrict__ W2,
                                                unsigned* __restrict__ h2s, int n) {
  __shared__ int accE[SLN * 33];
  __shared__ int accO[SLN * 33];
  __shared__ float W2s[64 * 16];
  __shared__ float dv[SLN];
  __shared__ float bb[64];
  int tid = threadIdx.x;
  int s = blockIdx.x;
  int node0 = s << SLB;
  int sn = min(SLN, n - node0);
  for (int i = tid; i < SLN * 33; i += ABLK) { accE[i] = 0; accO[i] = 0; }
  for (int i = tid; i < 1024; i += ABLK) W2s[i] = W2[i];
  if (tid < SLN) dv[tid] = (tid < sn) ? dinv[node0 + tid] : 0.f;
  if (tid < 64) bb[tid] = b1[tid];
  int e0 = s * SCAP;
  int cnt = min(cur[s], e0 + SCAP) - e0;  // multiple of 128 (padded)
  __syncthreads();

  int w = tid >> 6;         // wave 0..7
  int g4 = (tid >> 4) & 3;  // edge sub-slot within wave
  int l = tid & 15;         // owns dwords 2l, 2l+1 (features 4l..4l+3)
  for (int base = w * 16; base < cnt; base += 128) {
    int2 pk[U1];
#pragma unroll
    for (int u = 0; u < U1; u++) pk[u] = bpk[e0 + base + g4 + 4 * u];
    uint2 gg[U1];
#pragma unroll
    for (int u = 0; u < U1; u++)
      gg[u] = *(const uint2*)(h1s +
               (size_t)(unsigned)(pk[u].x & 0xFFFFF) * 32 + 2 * l);
#pragma unroll
    for (int u = 0; u < U1; u++) {
      int a = (int)((unsigned)pk[u].x >> 20) * 33 + 2 * l;
      float wt = __int_as_float(pk[u].y) * S1;
      atomicAdd(&accE[a],     __float2int_rn(wt * bflo(gg[u].x)));
      atomicAdd(&accO[a],     __float2int_rn(wt * bfhi(gg[u].x)));
      atomicAdd(&accE[a + 1], __float2int_rn(wt * bflo(gg[u].y)));
      atomicAdd(&accO[a + 1], __float2int_rn(wt * bfhi(gg[u].y)));
    }
  }
  __syncthreads();
  // F1: in-place relu rows: plane[k&1][node*33+(k>>1)] = relu(dv*(acc+self)+b1[k])
  for (int i = tid; i < SLN * 64; i += ABLK) {
    int node = i >> 6, k = i & 63;
    if (node < sn) {
      int v = node0 + node;
      unsigned us = h1s[(size_t)v * 32 + (k >> 1)];  // self (pre-scaled by dinv)
      float self = (k & 1) ? bfhi(us) : bflo(us);
      int* pl = (k & 1) ? accO : accE;
      int idx = node * 33 + (k >> 1);
      float a = pl[idx] * IS1;
      pl[idx] = __float_as_int(fmaxf(dv[node] * (a + self) + bb[k], 0.f));
    }
  }
  __syncthreads();
  // F2: GEMM2, 16 threads per node, 32 nodes per batch; h2s = dinv * (relu @ W2)
  int j = tid & 15;
  for (int nb = 0; nb < SLN; nb += 32) {
    int node = nb + (tid >> 4);  // 0..31
    float p = 0.f;
#pragma unroll
    for (int k = 0; k < 64; k++) {
      float rv = __int_as_float(((k & 1) ? accO : accE)[node * 33 + (k >> 1)]);
      p += rv * W2s[k * 16 + j];
    }
    p *= dv[node];
    float pp = __shfl_xor(p, 1, 64);
    if (node < sn && (j & 1) == 0)
      h2s[(size_t)(node0 + node) * 8 + (j >> 1)] =
          (unsigned)f2bf(p) | ((unsigned)f2bf(pp) << 16);
  }
}

// ---------------- layer-2: slice-LDS aggregate + bias + log_softmax ---------
// 512 threads. 4 lanes/edge, lane owns dword-pair -> 16 edges/wave-pass,
// maskless. acc stride 17.
__global__ __launch_bounds__(ABLK) void k_agg2s(const float* __restrict__ dinv,
                                                const int2* __restrict__ bpk,
                                                const int* __restrict__ cur,
                                                const unsigned* __restrict__ h2s,
                                                const float* __restrict__ b2,
                                                float* __restrict__ out, int n) {
  __shared__ int acc2[SLN * 17];
  int tid = threadIdx.x;
  int s = blockIdx.x;
  int node0 = s << SLB;
  int sn = min(SLN, n - node0);
  for (int i = tid; i < SLN * 17; i += ABLK) acc2[i] = 0;
  int e0 = s * SCAP;
  int cnt = min(cur[s], e0 + SCAP) - e0;  // multiple of 128 (padded)
  __syncthreads();

  int w = tid >> 6;          // wave 0..7
  int eg = (tid >> 2) & 15;  // edge slot within wave
  int m = tid & 3;           // owns dwords 2m, 2m+1 (features 4m..4m+3)
  for (int base = w * 16; base < cnt; base += 128) {
    int2 pk = bpk[e0 + base + eg];
    uint2 gg = *(const uint2*)(h2s +
               (size_t)(unsigned)(pk.x & 0xFFFFF) * 8 + 2 * m);
    int a = (int)((unsigned)pk.x >> 20) * 17 + 4 * m;
    float wt = __int_as_float(pk.y) * S1;
    atomicAdd(&acc2[a],     __float2int_rn(wt * bflo(gg.x)));
    atomicAdd(&acc2[a + 1], __float2int_rn(wt * bfhi(gg.x)));
    atomicAdd(&acc2[a + 2], __float2int_rn(wt * bflo(gg.y)));
    atomicAdd(&acc2[a + 3], __float2int_rn(wt * bfhi(gg.y)));
  }
  __syncthreads();
  // finalize: 16 threads per node, 32 nodes/batch, log_softmax in 16-lane group
  int f = tid & 15;
  for (int nb = 0; nb < SLN; nb += 32) {
    int node = nb + (tid >> 4);  // 0..31
    bool ok = node < sn;
    int v = node0 + min(node, sn - 1);
    float val = 0.f;
    if (ok) {
      float di = dinv[v];
      unsigned us = h2s[(size_t)v * 8 + (f >> 1)];  // self (pre-scaled)
      float self = (f & 1) ? bfhi(us) : bflo(us);
      val = di * (acc2[node * 17 + f] * IS1 + self) + b2[f];
    }
    float m2 = val;
    m2 = fmaxf(m2, __shfl_xor(m2, 1, 64));
    m2 = fmaxf(m2, __shfl_xor(m2, 2, 64));
    m2 = fmaxf(m2, __shfl_xor(m2, 4, 64));
    m2 = fmaxf(m2, __shfl_xor(m2, 8, 64));
    float ex = expf(val - m2);
    float ssum = ex;
    ssum += __shfl_xor(ssum, 1, 64);
    ssum += __shfl_xor(ssum, 2, 64);
    ssum += __shfl_xor(ssum, 4, 64);
    ssum += __shfl_xor(ssum, 8, 64);
    if (ok) out[(size_t)v * 16 + f] = val - m2 - logf(ssum);
  }
}

extern "C" void kernel_launch(void* const* d_in, const int* in_sizes, int n_in,
                              void* d_out, int out_size, void* d_ws, size_t ws_size,
                              hipStream_t stream) {
  const float* x  = (const float*)d_in[0];
  const int*   ei = (const int*)d_in[1];   // int32 [2,E]
  const float* ew = (const float*)d_in[2];
  const float* W1 = (const float*)d_in[3];
  const float* b1 = (const float*)d_in[4];
  const float* W2 = (const float*)d_in[5];
  const float* b2 = (const float*)d_in[6];
  float* out = (float*)d_out;

  int n = in_sizes[0] / 128;
  int E = in_sizes[2];
  const int* src = ei;
  const int* dst = ei + E;

  int NS = ((n - 1) >> SLB) + 1;  // 1563 for n=100k
  size_t padE = (size_t)NS * SCAP;

  char* wp = (char*)d_ws;
  auto alloc = [&](size_t bytes) -> char* {
    char* r = wp;
    wp += (bytes + 15) & ~(size_t)15;
    return r;
  };
  int*      cur  = (int*)alloc((size_t)(NS + 4) * 4);
  int2*     bpk  = (int2*)alloc(padE * 8);
  float*    dinv = (float*)alloc((size_t)n * 4);
  unsigned* h1s  = (unsigned*)alloc((size_t)n * 32 * 4);
  unsigned* h2s  = (unsigned*)alloc((size_t)n * 8 * 4);

  int gC = (E + CHUNK - 1) / CHUNK;  // 391

  k_zeroC<<<(NS + BLK - 1) / BLK, BLK, 0, stream>>>(cur, NS);
  k_bucket<<<gC, BBLK, 0, stream>>>(src, dst, ew, cur, bpk, n, E, NS);
  k_dinv<<<NS, BLK, 0, stream>>>(bpk, cur, dinv, n);
  k_gemm1<<<(n + 15) / 16, BLK, 0, stream>>>(x, W1, dinv, h1s, n);
  k_agg1s<<<NS, ABLK, 0, stream>>>(dinv, bpk, cur, h1s, b1, W2, h2s, n);
  k_agg2s<<<NS, ABLK, 0, stream>>>(dinv, bpk, cur, h2s, b2, out, n);
}

// Round 9
// 221.126 us; speedup vs baseline: 1.3167x; 1.1060x over previous
//
#include <hip/hip_runtime.h>
#include <cstdint>

#define BLK 256
#define ABLK 512           // agg kernels: 8 waves/block
#define BBLK 1024          // bucket: 16 waves/block (R7 lesson: occupancy must
                           // come from BLK, not grid — batching needs CHUNK>>NS)
#define EJ 4
#define CHUNK (BBLK * EJ)  // 4096 edges per bucket block, grid 391
#define SLB 6              // slice = 64 nodes
#define SLN 64
#define SCAP 1536          // mean 1024 @ E=1.6M/NS=1563; +16 sigma; 128-aligned
#define NSMAX 1600         // n <= 102400 supported

// Fixed-point scales for integer atomics (R2/R3 lesson: FP atomicAdd on LDS
// lowers to a CAS retry loop on gfx950 -> 9x stall; int ds_add_u32 is native).
#define S1   2097152.0f        // 2^21, layer-1/2 feature accumulators
#define IS1  (1.0f / 2097152.0f)
#define DSC  16777216.0f       // 2^24, degree accumulator
#define IDSC (1.0f / 16777216.0f)

typedef __attribute__((ext_vector_type(8))) short bf16x8;
typedef __attribute__((ext_vector_type(4))) float f32x4;

__device__ inline unsigned short f2bf(float f) {  // RNE
  unsigned u = __float_as_uint(f);
  return (unsigned short)((u + 0x7FFF + ((u >> 16) & 1)) >> 16);
}
__device__ inline float bflo(unsigned u) { return __uint_as_float(u << 16); }
__device__ inline float bfhi(unsigned u) { return __uint_as_float(u & 0xFFFF0000u); }

// split a,b into bf16-hi pair and bf16-lo (residual) pair, packed bf16x2
__device__ inline void splitpk(float a, float b, unsigned& h, unsigned& l) {
  unsigned short ha = f2bf(a), hb = f2bf(b);
  h = (unsigned)ha | ((unsigned)hb << 16);
  float ra = a - __uint_as_float((unsigned)ha << 16);
  float rb = b - __uint_as_float((unsigned)hb << 16);
  l = (unsigned)f2bf(ra) | ((unsigned)f2bf(rb) << 16);
}

// ---------------- init per-slice cursors to slice base ----------------
__global__ __launch_bounds__(BLK) void k_zeroC(int* __restrict__ cur, int NS) {
  int s = blockIdx.x * BLK + threadIdx.x;
  if (s < NS) cur[s] = s * SCAP;
}

// ---------------- bucket edges into fixed-capacity slice bins ----------------
// LDS histogram -> one batched reservation per (block,slice) -> LDS-cursor
// scatter. Single LDS array: c[s] is count, then global base, then cursor.
// 16 waves/block so the scattered 8B stores have TLP to hide under.
// bpk[p] = { (dstLocal<<20) | src, ew }   (requires n <= 2^20, dstLocal < 64)
__global__ __launch_bounds__(BBLK) void k_bucket(const int* __restrict__ src,
                                                 const int* __restrict__ dst,
                                                 const float* __restrict__ ew,
                                                 int* __restrict__ cur,
                                                 int2* __restrict__ bpk,
                                                 int n, int E, int NS) {
  __shared__ int c[NSMAX];
  int tid = threadIdx.x;
  for (int i = tid; i < NS; i += BBLK) c[i] = 0;
  __syncthreads();
  int base = blockIdx.x * CHUNK;
  int dloc[EJ];
#pragma unroll
  for (int j = 0; j < EJ; j++) {
    int idx = base + j * BBLK + tid;
    int d = -1;
    if (idx < E) {
      d = dst[idx];
      if ((unsigned)d >= (unsigned)n) d = -1;
    }
    dloc[j] = d;
    if (d >= 0) atomicAdd(&c[d >> SLB], 1);
  }
  __syncthreads();
  for (int s = tid; s < NS; s += BBLK) {
    int cc = c[s];
    if (cc) c[s] = atomicAdd(&cur[s], cc);  // c[s] becomes this block's cursor
  }
  __syncthreads();
#pragma unroll
  for (int j = 0; j < EJ; j++) {
    int idx = base + j * BBLK + tid;
    int d = dloc[j];
    if (d >= 0) {
      int s = d >> SLB;
      int p = atomicAdd(&c[s], 1);
      p = min(max(p, s * SCAP), (s + 1) * SCAP - 1);  // clamp into slice
      int packed = ((d & (SLN - 1)) << 20) | (src[idx] & 0xFFFFF);
      bpk[p] = make_int2(packed, __float_as_int(ew[idx]));
    }
  }
}

// ---------------- per-slice weighted in-degree -> dinv; pad slices ----------
// Pads each slice's edge list to a multiple of 128 with {0,0} dummies
// (dl=0, w=0 -> contributes nothing) so agg loops run maskless/clampless.
__global__ __launch_bounds__(BLK) void k_dinv(int2* __restrict__ bpk,
                                              int* __restrict__ cur,
                                              float* __restrict__ dinv, int n) {
  __shared__ int wsum[SLN];
  int s = blockIdx.x, tid = threadIdx.x;
  int node0 = s << SLB;
  int e0 = s * SCAP;
  int cnt = min(cur[s], e0 + SCAP) - e0;
  int cntP = min((cnt + 127) & ~127, SCAP);  // SCAP is 128-aligned
  if (tid < SLN) wsum[tid] = 0;
  for (int e = cnt + tid; e < cntP; e += BLK) bpk[e0 + e] = make_int2(0, 0);
  if (tid == 0) cur[s] = e0 + cntP;
  __syncthreads();
  for (int e = e0 + tid; e < e0 + cnt; e += BLK) {
    int2 pk = bpk[e];
    atomicAdd(&wsum[(unsigned)pk.x >> 20],
              __float2int_rn(__int_as_float(pk.y) * DSC));
  }
  __syncthreads();
  if (tid < SLN && node0 + tid < n)
    dinv[node0 + tid] = rsqrtf(1.0f + wsum[tid] * IDSC);  // deg >= 1 (self loop)
}

// ---------------- GEMM1 (MFMA bf16x3): h1s = dinv * (x @ W1), fp32-faithful --
// R9: old fp32-VALU version was issue-bound (58us, VALUBusy 63%, 5 LDS reads
// per 4 FMA). bf16x3 split: x=xh+xl, W=Wh+Wl; h ~= xh@Wh + xl@Wh + xh@Wl
// (residual ~2^-17 rel, << bf16 storage error). Block = 64 rows x 64 cols,
// 4 waves x 16 rows, K=128 = 4 ksteps. W staged per block as pre-swizzled
// hi/lo B-frags in LDS. Frag layout (m89/m97-verified): A/B lane&15 = row/col,
// 8 k-contig at (lane>>4)*8; C/D col=lane&15, row=(lane>>4)*4+reg.
__global__ __launch_bounds__(BLK) void k_gemm1(const float* __restrict__ x,
                                               const float* __restrict__ W,
                                               const float* __restrict__ dinv,
                                               unsigned* __restrict__ h1s, int n) {
  __shared__ unsigned Wh[4][4][64][4];  // [kstep][coltile][lane][dword]
  __shared__ unsigned Wl[4][4][64][4];
  int tid = threadIdx.x;
  for (int i = tid; i < 4096; i += BLK) {
    int dw = i & 3, lane = (i >> 2) & 63, ct = (i >> 8) & 3, ks = i >> 10;
    int col = ct * 16 + (lane & 15);
    int kb = ks * 32 + ((lane >> 4) << 3) + dw * 2;
    unsigned h, l;
    splitpk(W[kb * 64 + col], W[(kb + 1) * 64 + col], h, l);
    Wh[ks][ct][lane][dw] = h;
    Wl[ks][ct][lane][dw] = l;
  }
  __syncthreads();

  int w = tid >> 6, l = tid & 63;
  int rowA = blockIdx.x * 64 + w * 16 + (l & 15);    // row this lane LOADS
  int rowAc = min(rowA, n - 1);
  int kg = l >> 4;
  const float4* xr = (const float4*)(x + (size_t)rowAc * 128);

  f32x4 acc[4];
#pragma unroll
  for (int ct = 0; ct < 4; ct++) acc[ct] = (f32x4){0.f, 0.f, 0.f, 0.f};

  union Frag { unsigned u[4]; bf16x8 s; };
#pragma unroll
  for (int ks = 0; ks < 4; ks++) {
    float4 f0 = xr[ks * 8 + kg * 2];
    float4 f1 = xr[ks * 8 + kg * 2 + 1];
    Frag Ah, Al;
    splitpk(f0.x, f0.y, Ah.u[0], Al.u[0]);
    splitpk(f0.z, f0.w, Ah.u[1], Al.u[1]);
    splitpk(f1.x, f1.y, Ah.u[2], Al.u[2]);
    splitpk(f1.z, f1.w, Ah.u[3], Al.u[3]);
#pragma unroll
    for (int ct = 0; ct < 4; ct++) {
      Frag Bh, Bl;
      *(uint4*)Bh.u = *(const uint4*)Wh[ks][ct][l];
      *(uint4*)Bl.u = *(const uint4*)Wl[ks][ct][l];
      acc[ct] = __builtin_amdgcn_mfma_f32_16x16x32_bf16(Ah.s, Bh.s, acc[ct], 0, 0, 0);
      acc[ct] = __builtin_amdgcn_mfma_f32_16x16x32_bf16(Al.s, Bh.s, acc[ct], 0, 0, 0);
      acc[ct] = __builtin_amdgcn_mfma_f32_16x16x32_bf16(Ah.s, Bl.s, acc[ct], 0, 0, 0);
    }
  }

  // epilogue: lane owns col = ct*16 + (l&15), rows (l>>4)*4 + r
  int rbase = blockIdx.x * 64 + w * 16 + (l >> 4) * 4;
  float di[4];
#pragma unroll
  for (int r = 0; r < 4; r++) di[r] = dinv[min(rbase + r, n - 1)];
  int cl = l & 15;
#pragma unroll
  for (int ct = 0; ct < 4; ct++) {
#pragma unroll
    for (int r = 0; r < 4; r++) {
      float v = acc[ct][r] * di[r];
      float vp = __shfl_xor(v, 1, 64);
      if ((cl & 1) == 0 && rbase + r < n)
        h1s[(size_t)(rbase + r) * 32 + ct * 8 + (cl >> 1)] =
            (unsigned)f2bf(v) | ((unsigned)f2bf(vp) << 16);
    }
  }
}

// ---------------- layer-1: slice-LDS aggregate + bias + ReLU + GEMM2 --------
// Block = slice of 64 nodes, 512 threads. 16 lanes/edge, lane owns a
// dword-pair (uint2 gather) -> 4 edges per wave-pass; maskless (slices
// 128-padded by k_dinv). Fixed-point int LDS accumulators (native ds_add_u32),
// two planes, stride 33.
#define U1 4
__global__ __launch_bounds__(ABLK) void k_agg1s(const float* __restrict__ dinv,
                                                const int2* __restrict__ bpk,
                                                const int* __restrict__ cur,
                                                const unsigned* __restrict__ h1s,
                                                const float* __restrict__ b1,
                                                const float* __restrict__ W2,
                                                unsigned* __restrict__ h2s, int n) {
  __shared__ int accE[SLN * 33];
  __shared__ int accO[SLN * 33];
  __shared__ float W2s[64 * 16];
  __shared__ float dv[SLN];
  __shared__ float bb[64];
  int tid = threadIdx.x;
  int s = blockIdx.x;
  int node0 = s << SLB;
  int sn = min(SLN, n - node0);
  for (int i = tid; i < SLN * 33; i += ABLK) { accE[i] = 0; accO[i] = 0; }
  for (int i = tid; i < 1024; i += ABLK) W2s[i] = W2[i];
  if (tid < SLN) dv[tid] = (tid < sn) ? dinv[node0 + tid] : 0.f;
  if (tid < 64) bb[tid] = b1[tid];
  int e0 = s * SCAP;
  int cnt = min(cur[s], e0 + SCAP) - e0;  // multiple of 128 (padded)
  __syncthreads();

  int w = tid >> 6;         // wave 0..7
  int g4 = (tid >> 4) & 3;  // edge sub-slot within wave
  int l = tid & 15;         // owns dwords 2l, 2l+1 (features 4l..4l+3)
  for (int base = w * 16; base < cnt; base += 128) {
    int2 pk[U1];
#pragma unroll
    for (int u = 0; u < U1; u++) pk[u] = bpk[e0 + base + g4 + 4 * u];
    uint2 gg[U1];
#pragma unroll
    for (int u = 0; u < U1; u++)
      gg[u] = *(const uint2*)(h1s +
               (size_t)(unsigned)(pk[u].x & 0xFFFFF) * 32 + 2 * l);
#pragma unroll
    for (int u = 0; u < U1; u++) {
      int a = (int)((unsigned)pk[u].x >> 20) * 33 + 2 * l;
      float wt = __int_as_float(pk[u].y) * S1;
      atomicAdd(&accE[a],     __float2int_rn(wt * bflo(gg[u].x)));
      atomicAdd(&accO[a],     __float2int_rn(wt * bfhi(gg[u].x)));
      atomicAdd(&accE[a + 1], __float2int_rn(wt * bflo(gg[u].y)));
      atomicAdd(&accO[a + 1], __float2int_rn(wt * bfhi(gg[u].y)));
    }
  }
  __syncthreads();
  // F1: in-place relu rows: plane[k&1][node*33+(k>>1)] = relu(dv*(acc+self)+b1[k])
  for (int i = tid; i < SLN * 64; i += ABLK) {
    int node = i >> 6, k = i & 63;
    if (node < sn) {
      int v = node0 + node;
      unsigned us = h1s[(size_t)v * 32 + (k >> 1)];  // self (pre-scaled by dinv)
      float self = (k & 1) ? bfhi(us) : bflo(us);
      int* pl = (k & 1) ? accO : accE;
      int idx = node * 33 + (k >> 1);
      float a = pl[idx] * IS1;
      pl[idx] = __float_as_int(fmaxf(dv[node] * (a + self) + bb[k], 0.f));
    }
  }
  __syncthreads();
  // F2: GEMM2, 16 threads per node, 32 nodes per batch; h2s = dinv * (relu @ W2)
  int j = tid & 15;
  for (int nb = 0; nb < SLN; nb += 32) {
    int node = nb + (tid >> 4);  // 0..31
    float p = 0.f;
#pragma unroll
    for (int k = 0; k < 64; k++) {
      float rv = __int_as_float(((k & 1) ? accO : accE)[node * 33 + (k >> 1)]);
      p += rv * W2s[k * 16 + j];
    }
    p *= dv[node];
    float pp = __shfl_xor(p, 1, 64);
    if (node < sn && (j & 1) == 0)
      h2s[(size_t)(node0 + node) * 8 + (j >> 1)] =
          (unsigned)f2bf(p) | ((unsigned)f2bf(pp) << 16);
  }
}

// ---------------- layer-2: slice-LDS aggregate + bias + log_softmax ---------
// 512 threads. 4 lanes/edge, lane owns dword-pair -> 16 edges/wave-pass,
// maskless. acc stride 17.
__global__ __launch_bounds__(ABLK) void k_agg2s(const float* __restrict__ dinv,
                                                const int2* __restrict__ bpk,
                                                const int* __restrict__ cur,
                                                const unsigned* __restrict__ h2s,
                                                const float* __restrict__ b2,
                                                float* __restrict__ out, int n) {
  __shared__ int acc2[SLN * 17];
  int tid = threadIdx.x;
  int s = blockIdx.x;
  int node0 = s << SLB;
  int sn = min(SLN, n - node0);
  for (int i = tid; i < SLN * 17; i += ABLK) acc2[i] = 0;
  int e0 = s * SCAP;
  int cnt = min(cur[s], e0 + SCAP) - e0;  // multiple of 128 (padded)
  __syncthreads();

  int w = tid >> 6;          // wave 0..7
  int eg = (tid >> 2) & 15;  // edge slot within wave
  int m = tid & 3;           // owns dwords 2m, 2m+1 (features 4m..4m+3)
  for (int base = w * 16; base < cnt; base += 128) {
    int2 pk = bpk[e0 + base + eg];
    uint2 gg = *(const uint2*)(h2s +
               (size_t)(unsigned)(pk.x & 0xFFFFF) * 8 + 2 * m);
    int a = (int)((unsigned)pk.x >> 20) * 17 + 4 * m;
    float wt = __int_as_float(pk.y) * S1;
    atomicAdd(&acc2[a],     __float2int_rn(wt * bflo(gg.x)));
    atomicAdd(&acc2[a + 1], __float2int_rn(wt * bfhi(gg.x)));
    atomicAdd(&acc2[a + 2], __float2int_rn(wt * bflo(gg.y)));
    atomicAdd(&acc2[a + 3], __float2int_rn(wt * bfhi(gg.y)));
  }
  __syncthreads();
  // finalize: 16 threads per node, 32 nodes/batch, log_softmax in 16-lane group
  int f = tid & 15;
  for (int nb = 0; nb < SLN; nb += 32) {
    int node = nb + (tid >> 4);  // 0..31
    bool ok = node < sn;
    int v = node0 + min(node, sn - 1);
    float val = 0.f;
    if (ok) {
      float di = dinv[v];
      unsigned us = h2s[(size_t)v * 8 + (f >> 1)];  // self (pre-scaled)
      float self = (f & 1) ? bfhi(us) : bflo(us);
      val = di * (acc2[node * 17 + f] * IS1 + self) + b2[f];
    }
    float m2 = val;
    m2 = fmaxf(m2, __shfl_xor(m2, 1, 64));
    m2 = fmaxf(m2, __shfl_xor(m2, 2, 64));
    m2 = fmaxf(m2, __shfl_xor(m2, 4, 64));
    m2 = fmaxf(m2, __shfl_xor(m2, 8, 64));
    float ex = expf(val - m2);
    float ssum = ex;
    ssum += __shfl_xor(ssum, 1, 64);
    ssum += __shfl_xor(ssum, 2, 64);
    ssum += __shfl_xor(ssum, 4, 64);
    ssum += __shfl_xor(ssum, 8, 64);
    if (ok) out[(size_t)v * 16 + f] = val - m2 - logf(ssum);
  }
}

extern "C" void kernel_launch(void* const* d_in, const int* in_sizes, int n_in,
                              void* d_out, int out_size, void* d_ws, size_t ws_size,
                              hipStream_t stream) {
  const float* x  = (const float*)d_in[0];
  const int*   ei = (const int*)d_in[1];   // int32 [2,E]
  const float* ew = (const float*)d_in[2];
  const float* W1 = (const float*)d_in[3];
  const float* b1 = (const float*)d_in[4];
  const float* W2 = (const float*)d_in[5];
  const float* b2 = (const float*)d_in[6];
  float* out = (float*)d_out;

  int n = in_sizes[0] / 128;
  int E = in_sizes[2];
  const int* src = ei;
  const int* dst = ei + E;

  int NS = ((n - 1) >> SLB) + 1;  // 1563 for n=100k
  size_t padE = (size_t)NS * SCAP;

  char* wp = (char*)d_ws;
  auto alloc = [&](size_t bytes) -> char* {
    char* r = wp;
    wp += (bytes + 15) & ~(size_t)15;
    return r;
  };
  int*      cur  = (int*)alloc((size_t)(NS + 4) * 4);
  int2*     bpk  = (int2*)alloc(padE * 8);
  float*    dinv = (float*)alloc((size_t)n * 4);
  unsigned* h1s  = (unsigned*)alloc((size_t)n * 32 * 4);
  unsigned* h2s  = (unsigned*)alloc((size_t)n * 8 * 4);

  int gC = (E + CHUNK - 1) / CHUNK;  // 391

  k_zeroC<<<(NS + BLK - 1) / BLK, BLK, 0, stream>>>(cur, NS);
  k_bucket<<<gC, BBLK, 0, stream>>>(src, dst, ew, cur, bpk, n, E, NS);
  k_dinv<<<NS, BLK, 0, stream>>>(bpk, cur, dinv, n);
  k_gemm1<<<(n + 63) / 64, BLK, 0, stream>>>(x, W1, dinv, h1s, n);
  k_agg1s<<<NS, ABLK, 0, stream>>>(dinv, bpk, cur, h1s, b1, W2, h2s, n);
  k_agg2s<<<NS, ABLK, 0, stream>>>(dinv, bpk, cur, h2s, b2, out, n);
}

// Round 10
// 218.330 us; speedup vs baseline: 1.3336x; 1.0128x over previous
//
#include <hip/hip_runtime.h>
#include <cstdint>

#define BLK 256
#define ABLK 512           // agg kernels: 8 waves/block
#define BBLK 1024          // bucket: 16 waves/block (R7 lesson: occupancy must
                           // come from BLK, not grid — batching needs CHUNK>>NS)
#define EJ 4
#define CHUNK (BBLK * EJ)  // 4096 edges per bucket block, grid 391
#define SLB 6              // slice = 64 nodes
#define SLN 64
#define SCAP 1536          // mean 1024 @ E=1.6M/NS=1563; +16 sigma; 128-aligned
#define NSMAX 1600         // n <= 102400 supported

// Fixed-point scales for integer atomics (R2/R3 lesson: FP atomicAdd on LDS
// lowers to a CAS retry loop on gfx950 -> 9x stall; int ds_add_u32 is native).
#define S1   2097152.0f        // 2^21, layer-1/2 feature accumulators
#define IS1  (1.0f / 2097152.0f)
#define DSC  16777216.0f       // 2^24, degree accumulator
#define IDSC (1.0f / 16777216.0f)

typedef __attribute__((ext_vector_type(8))) short bf16x8;
typedef __attribute__((ext_vector_type(4))) float f32x4;

__device__ inline unsigned short f2bf(float f) {  // RNE
  unsigned u = __float_as_uint(f);
  return (unsigned short)((u + 0x7FFF + ((u >> 16) & 1)) >> 16);
}
__device__ inline float bflo(unsigned u) { return __uint_as_float(u << 16); }
__device__ inline float bfhi(unsigned u) { return __uint_as_float(u & 0xFFFF0000u); }

// split a,b into bf16-hi pair and bf16-lo (residual) pair, packed bf16x2
__device__ inline void splitpk(float a, float b, unsigned& h, unsigned& l) {
  unsigned short ha = f2bf(a), hb = f2bf(b);
  h = (unsigned)ha | ((unsigned)hb << 16);
  float ra = a - __uint_as_float((unsigned)ha << 16);
  float rb = b - __uint_as_float((unsigned)hb << 16);
  l = (unsigned)f2bf(ra) | ((unsigned)f2bf(rb) << 16);
}

// ---------------- init per-slice cursors to slice base ----------------
__global__ __launch_bounds__(BLK) void k_zeroC(int* __restrict__ cur, int NS) {
  int s = blockIdx.x * BLK + threadIdx.x;
  if (s < NS) cur[s] = s * SCAP;
}

// ---------------- bucket edges into fixed-capacity slice bins ----------------
// LDS histogram -> one batched reservation per (block,slice) -> LDS-cursor
// scatter. Single LDS array: c[s] is count, then global base, then cursor.
// 16 waves/block so the scattered 8B stores have TLP to hide under.
// bpk[p] = { (dstLocal<<20) | src, ew }   (requires n <= 2^20, dstLocal < 64)
__global__ __launch_bounds__(BBLK) void k_bucket(const int* __restrict__ src,
                                                 const int* __restrict__ dst,
                                                 const float* __restrict__ ew,
                                                 int* __restrict__ cur,
                                                 int2* __restrict__ bpk,
                                                 int n, int E, int NS) {
  __shared__ int c[NSMAX];
  int tid = threadIdx.x;
  for (int i = tid; i < NS; i += BBLK) c[i] = 0;
  __syncthreads();
  int base = blockIdx.x * CHUNK;
  int dloc[EJ];
#pragma unroll
  for (int j = 0; j < EJ; j++) {
    int idx = base + j * BBLK + tid;
    int d = -1;
    if (idx < E) {
      d = dst[idx];
      if ((unsigned)d >= (unsigned)n) d = -1;
    }
    dloc[j] = d;
    if (d >= 0) atomicAdd(&c[d >> SLB], 1);
  }
  __syncthreads();
  for (int s = tid; s < NS; s += BBLK) {
    int cc = c[s];
    if (cc) c[s] = atomicAdd(&cur[s], cc);  // c[s] becomes this block's cursor
  }
  __syncthreads();
#pragma unroll
  for (int j = 0; j < EJ; j++) {
    int idx = base + j * BBLK + tid;
    int d = dloc[j];
    if (d >= 0) {
      int s = d >> SLB;
      int p = atomicAdd(&c[s], 1);
      p = min(max(p, s * SCAP), (s + 1) * SCAP - 1);  // clamp into slice
      int packed = ((d & (SLN - 1)) << 20) | (src[idx] & 0xFFFFF);
      bpk[p] = make_int2(packed, __float_as_int(ew[idx]));
    }
  }
}

// ---------------- per-slice weighted in-degree -> dinv; pad slices ----------
// Pads each slice's edge list to a multiple of 128 with {0,0} dummies
// (dl=0, w=0 -> contributes nothing) so agg loops run maskless/clampless.
__global__ __launch_bounds__(BLK) void k_dinv(int2* __restrict__ bpk,
                                              int* __restrict__ cur,
                                              float* __restrict__ dinv, int n) {
  __shared__ int wsum[SLN];
  int s = blockIdx.x, tid = threadIdx.x;
  int node0 = s << SLB;
  int e0 = s * SCAP;
  int cnt = min(cur[s], e0 + SCAP) - e0;
  int cntP = min((cnt + 127) & ~127, SCAP);  // SCAP is 128-aligned
  if (tid < SLN) wsum[tid] = 0;
  for (int e = cnt + tid; e < cntP; e += BLK) bpk[e0 + e] = make_int2(0, 0);
  if (tid == 0) cur[s] = e0 + cntP;
  __syncthreads();
  for (int e = e0 + tid; e < e0 + cnt; e += BLK) {
    int2 pk = bpk[e];
    atomicAdd(&wsum[(unsigned)pk.x >> 20],
              __float2int_rn(__int_as_float(pk.y) * DSC));
  }
  __syncthreads();
  if (tid < SLN && node0 + tid < n)
    dinv[node0 + tid] = rsqrtf(1.0f + wsum[tid] * IDSC);  // deg >= 1 (self loop)
}

// ---------------- GEMM1 (MFMA bf16x3): h1s = dinv * (x @ W1), fp32-faithful --
// bf16x3 split: x=xh+xl, W=Wh+Wl; h ~= xh@Wh + xl@Wh + xh@Wl (residual ~2^-17
// rel). Block = 64 rows x 64 cols, 4 waves x 16 rows, K=128 = 4 ksteps.
// Frag layout (m89/m97-verified): A/B lane&15 = row/col, 8 k-contig at
// (lane>>4)*8; C/D col=lane&15, row=(lane>>4)*4+reg.
__global__ __launch_bounds__(BLK) void k_gemm1(const float* __restrict__ x,
                                               const float* __restrict__ W,
                                               const float* __restrict__ dinv,
                                               unsigned* __restrict__ h1s, int n) {
  __shared__ unsigned Wh[4][4][64][4];  // [kstep][coltile][lane][dword]
  __shared__ unsigned Wl[4][4][64][4];
  int tid = threadIdx.x;
  for (int i = tid; i < 4096; i += BLK) {
    int dw = i & 3, lane = (i >> 2) & 63, ct = (i >> 8) & 3, ks = i >> 10;
    int col = ct * 16 + (lane & 15);
    int kb = ks * 32 + ((lane >> 4) << 3) + dw * 2;
    unsigned h, l;
    splitpk(W[kb * 64 + col], W[(kb + 1) * 64 + col], h, l);
    Wh[ks][ct][lane][dw] = h;
    Wl[ks][ct][lane][dw] = l;
  }
  __syncthreads();

  int w = tid >> 6, l = tid & 63;
  int rowA = blockIdx.x * 64 + w * 16 + (l & 15);    // row this lane LOADS
  int rowAc = min(rowA, n - 1);
  int kg = l >> 4;
  const float4* xr = (const float4*)(x + (size_t)rowAc * 128);

  f32x4 acc[4];
#pragma unroll
  for (int ct = 0; ct < 4; ct++) acc[ct] = (f32x4){0.f, 0.f, 0.f, 0.f};

  union Frag { unsigned u[4]; bf16x8 s; };
#pragma unroll
  for (int ks = 0; ks < 4; ks++) {
    float4 f0 = xr[ks * 8 + kg * 2];
    float4 f1 = xr[ks * 8 + kg * 2 + 1];
    Frag Ah, Al;
    splitpk(f0.x, f0.y, Ah.u[0], Al.u[0]);
    splitpk(f0.z, f0.w, Ah.u[1], Al.u[1]);
    splitpk(f1.x, f1.y, Ah.u[2], Al.u[2]);
    splitpk(f1.z, f1.w, Ah.u[3], Al.u[3]);
#pragma unroll
    for (int ct = 0; ct < 4; ct++) {
      Frag Bh, Bl;
      *(uint4*)Bh.u = *(const uint4*)Wh[ks][ct][l];
      *(uint4*)Bl.u = *(const uint4*)Wl[ks][ct][l];
      acc[ct] = __builtin_amdgcn_mfma_f32_16x16x32_bf16(Ah.s, Bh.s, acc[ct], 0, 0, 0);
      acc[ct] = __builtin_amdgcn_mfma_f32_16x16x32_bf16(Al.s, Bh.s, acc[ct], 0, 0, 0);
      acc[ct] = __builtin_amdgcn_mfma_f32_16x16x32_bf16(Ah.s, Bl.s, acc[ct], 0, 0, 0);
    }
  }

  // epilogue: lane owns col = ct*16 + (l&15), rows (l>>4)*4 + r
  int rbase = blockIdx.x * 64 + w * 16 + (l >> 4) * 4;
  float di[4];
#pragma unroll
  for (int r = 0; r < 4; r++) di[r] = dinv[min(rbase + r, n - 1)];
  int cl = l & 15;
#pragma unroll
  for (int ct = 0; ct < 4; ct++) {
#pragma unroll
    for (int r = 0; r < 4; r++) {
      float v = acc[ct][r] * di[r];
      float vp = __shfl_xor(v, 1, 64);
      if ((cl & 1) == 0 && rbase + r < n)
        h1s[(size_t)(rbase + r) * 32 + ct * 8 + (cl >> 1)] =
            (unsigned)f2bf(v) | ((unsigned)f2bf(vp) << 16);
    }
  }
}

// ---------------- layer-1: slice-LDS aggregate + bias + ReLU + GEMM2 --------
// Block = slice of 64 nodes, 512 threads. 16 lanes/edge, lane owns a
// dword-pair (uint2 gather); maskless (slices 128-padded by k_dinv).
// R10: U1 4->8 — 8 gathers in flight per lane (VGPR was 24, huge headroom;
// gather latency to L3/HBM was exposed at 4-deep). Fixed-point int LDS
// accumulators (native ds_add_u32), two planes, stride 33.
#define U1 8
__global__ __launch_bounds__(ABLK) void k_agg1s(const float* __restrict__ dinv,
                                                const int2* __restrict__ bpk,
                                                const int* __restrict__ cur,
                                                const unsigned* __restrict__ h1s,
                                                const float* __restrict__ b1,
                                                const float* __restrict__ W2,
                                                unsigned* __restrict__ h2s, int n) {
  __shared__ int accE[SLN * 33];
  __shared__ int accO[SLN * 33];
  __shared__ float W2s[64 * 16];
  __shared__ float dv[SLN];
  __shared__ float bb[64];
  int tid = threadIdx.x;
  int s = blockIdx.x;
  int node0 = s << SLB;
  int sn = min(SLN, n - node0);
  for (int i = tid; i < SLN * 33; i += ABLK) { accE[i] = 0; accO[i] = 0; }
  for (int i = tid; i < 1024; i += ABLK) W2s[i] = W2[i];
  if (tid < SLN) dv[tid] = (tid < sn) ? dinv[node0 + tid] : 0.f;
  if (tid < 64) bb[tid] = b1[tid];
  int e0 = s * SCAP;
  int cnt = min(cur[s], e0 + SCAP) - e0;  // multiple of 128 (padded)
  __syncthreads();

  int w = tid >> 6;         // wave 0..7
  int g4 = (tid >> 4) & 3;  // edge sub-slot within wave
  int l = tid & 15;         // owns dwords 2l, 2l+1 (features 4l..4l+3)
  const unsigned* hp = h1s + 2 * l;
  for (int base = w * 32; base < cnt; base += 256) {  // 32 edges/wave-iter
    int2 pk[U1];
#pragma unroll
    for (int u = 0; u < U1; u++) pk[u] = bpk[e0 + base + g4 + 4 * u];
    uint2 gg[U1];
#pragma unroll
    for (int u = 0; u < U1; u++)
      gg[u] = *(const uint2*)(hp + (size_t)(unsigned)(pk[u].x & 0xFFFFF) * 32);
#pragma unroll
    for (int u = 0; u < U1; u++) {
      int a = (int)((unsigned)pk[u].x >> 20) * 33 + 2 * l;
      float wt = __int_as_float(pk[u].y) * S1;
      atomicAdd(&accE[a],     __float2int_rn(wt * bflo(gg[u].x)));
      atomicAdd(&accO[a],     __float2int_rn(wt * bfhi(gg[u].x)));
      atomicAdd(&accE[a + 1], __float2int_rn(wt * bflo(gg[u].y)));
      atomicAdd(&accO[a + 1], __float2int_rn(wt * bfhi(gg[u].y)));
    }
  }
  __syncthreads();
  // F1: in-place relu rows: plane[k&1][node*33+(k>>1)] = relu(dv*(acc+self)+b1[k])
  for (int i = tid; i < SLN * 64; i += ABLK) {
    int node = i >> 6, k = i & 63;
    if (node < sn) {
      int v = node0 + node;
      unsigned us = h1s[(size_t)v * 32 + (k >> 1)];  // self (pre-scaled by dinv)
      float self = (k & 1) ? bfhi(us) : bflo(us);
      int* pl = (k & 1) ? accO : accE;
      int idx = node * 33 + (k >> 1);
      float a = pl[idx] * IS1;
      pl[idx] = __float_as_int(fmaxf(dv[node] * (a + self) + bb[k], 0.f));
    }
  }
  __syncthreads();
  // F2: GEMM2, 16 threads per node, 32 nodes per batch; h2s = dinv * (relu @ W2)
  int j = tid & 15;
  for (int nb = 0; nb < SLN; nb += 32) {
    int node = nb + (tid >> 4);  // 0..31
    float p = 0.f;
#pragma unroll
    for (int k = 0; k < 64; k++) {
      float rv = __int_as_float(((k & 1) ? accO : accE)[node * 33 + (k >> 1)]);
      p += rv * W2s[k * 16 + j];
    }
    p *= dv[node];
    float pp = __shfl_xor(p, 1, 64);
    if (node < sn && (j & 1) == 0)
      h2s[(size_t)(node0 + node) * 8 + (j >> 1)] =
          (unsigned)f2bf(p) | ((unsigned)f2bf(pp) << 16);
  }
}

// ---------------- layer-2: slice-LDS aggregate + bias + log_softmax ---------
// 512 threads. 4 lanes/edge, lane owns dword-pair. R10: 4-deep gather
// pipeline (was 1 in flight). Maskless. acc stride 17.
#define U2 4
__global__ __launch_bounds__(ABLK) void k_agg2s(const float* __restrict__ dinv,
                                                const int2* __restrict__ bpk,
                                                const int* __restrict__ cur,
                                                const unsigned* __restrict__ h2s,
                                                const float* __restrict__ b2,
                                                float* __restrict__ out, int n) {
  __shared__ int acc2[SLN * 17];
  int tid = threadIdx.x;
  int s = blockIdx.x;
  int node0 = s << SLB;
  int sn = min(SLN, n - node0);
  for (int i = tid; i < SLN * 17; i += ABLK) acc2[i] = 0;
  int e0 = s * SCAP;
  int cnt = min(cur[s], e0 + SCAP) - e0;  // multiple of 128 (padded)
  __syncthreads();

  int w = tid >> 6;          // wave 0..7
  int eg = (tid >> 2) & 15;  // edge slot within wave
  int m = tid & 3;           // owns dwords 2m, 2m+1 (features 4m..4m+3)
  const unsigned* hp = h2s + 2 * m;
  for (int base = w * 64; base < cnt; base += 512) {  // 64 edges/wave-iter
    int2 pk[U2];
#pragma unroll
    for (int u = 0; u < U2; u++) pk[u] = bpk[e0 + base + eg + 16 * u];
    uint2 gg[U2];
#pragma unroll
    for (int u = 0; u < U2; u++)
      gg[u] = *(const uint2*)(hp + (size_t)(unsigned)(pk[u].x & 0xFFFFF) * 8);
#pragma unroll
    for (int u = 0; u < U2; u++) {
      int a = (int)((unsigned)pk[u].x >> 20) * 17 + 4 * m;
      float wt = __int_as_float(pk[u].y) * S1;
      atomicAdd(&acc2[a],     __float2int_rn(wt * bflo(gg[u].x)));
      atomicAdd(&acc2[a + 1], __float2int_rn(wt * bfhi(gg[u].x)));
      atomicAdd(&acc2[a + 2], __float2int_rn(wt * bflo(gg[u].y)));
      atomicAdd(&acc2[a + 3], __float2int_rn(wt * bfhi(gg[u].y)));
    }
  }
  __syncthreads();
  // finalize: 16 threads per node, 32 nodes/batch, log_softmax in 16-lane group
  int f = tid & 15;
  for (int nb = 0; nb < SLN; nb += 32) {
    int node = nb + (tid >> 4);  // 0..31
    bool ok = node < sn;
    int v = node0 + min(node, sn - 1);
    float val = 0.f;
    if (ok) {
      float di = dinv[v];
      unsigned us = h2s[(size_t)v * 8 + (f >> 1)];  // self (pre-scaled)
      float self = (f & 1) ? bfhi(us) : bflo(us);
      val = di * (acc2[node * 17 + f] * IS1 + self) + b2[f];
    }
    float m2 = val;
    m2 = fmaxf(m2, __shfl_xor(m2, 1, 64));
    m2 = fmaxf(m2, __shfl_xor(m2, 2, 64));
    m2 = fmaxf(m2, __shfl_xor(m2, 4, 64));
    m2 = fmaxf(m2, __shfl_xor(m2, 8, 64));
    float ex = expf(val - m2);
    float ssum = ex;
    ssum += __shfl_xor(ssum, 1, 64);
    ssum += __shfl_xor(ssum, 2, 64);
    ssum += __shfl_xor(ssum, 4, 64);
    ssum += __shfl_xor(ssum, 8, 64);
    if (ok) out[(size_t)v * 16 + f] = val - m2 - logf(ssum);
  }
}

extern "C" void kernel_launch(void* const* d_in, const int* in_sizes, int n_in,
                              void* d_out, int out_size, void* d_ws, size_t ws_size,
                              hipStream_t stream) {
  const float* x  = (const float*)d_in[0];
  const int*   ei = (const int*)d_in[1];   // int32 [2,E]
  const float* ew = (const float*)d_in[2];
  const float* W1 = (const float*)d_in[3];
  const float* b1 = (const float*)d_in[4];
  const float* W2 = (const float*)d_in[5];
  const float* b2 = (const float*)d_in[6];
  float* out = (float*)d_out;

  int n = in_sizes[0] / 128;
  int E = in_sizes[2];
  const int* src = ei;
  const int* dst = ei + E;

  int NS = ((n - 1) >> SLB) + 1;  // 1563 for n=100k
  size_t padE = (size_t)NS * SCAP;

  char* wp = (char*)d_ws;
  auto alloc = [&](size_t bytes) -> char* {
    char* r = wp;
    wp += (bytes + 15) & ~(size_t)15;
    return r;
  };
  int*      cur  = (int*)alloc((size_t)(NS + 4) * 4);
  int2*     bpk  = (int2*)alloc(padE * 8);
  float*    dinv = (float*)alloc((size_t)n * 4);
  unsigned* h1s  = (unsigned*)alloc((size_t)n * 32 * 4);
  unsigned* h2s  = (unsigned*)alloc((size_t)n * 8 * 4);

  int gC = (E + CHUNK - 1) / CHUNK;  // 391

  k_zeroC<<<(NS + BLK - 1) / BLK, BLK, 0, stream>>>(cur, NS);
  k_bucket<<<gC, BBLK, 0, stream>>>(src, dst, ew, cur, bpk, n, E, NS);
  k_dinv<<<NS, BLK, 0, stream>>>(bpk, cur, dinv, n);
  k_gemm1<<<(n + 63) / 64, BLK, 0, stream>>>(x, W1, dinv, h1s, n);
  k_agg1s<<<NS, ABLK, 0, stream>>>(dinv, bpk, cur, h1s, b1, W2, h2s, n);
  k_agg2s<<<NS, ABLK, 0, stream>>>(dinv, bpk, cur, h2s, b2, out, n);
}